// Round 7
// baseline (176.229 us; speedup 1.0000x reference)
//
#include <hip/hip_runtime.h>

#define NB 256
#define NC 256
#define NL 25
#define ND 257
#define NHID 64
#define NOUT 32

// dynamic LDS layout (float offsets)
#define OFF_H0   0        // 24576 floats: h0 chunk, 6 batches x 64 pairs x 64 k (96 KB)
                          //   aliases: xs (6400 floats, phase 1) ; red (64x264, final reduce)
#define OFF_P    24576    // 6400 floats: P[chalf][uv][25][64]
#define OFF_B0   30976    // 64
#define OFF_SF   31040    // 64
#define OFF_Z    31104    // 64
#define SMEM_FLOATS 31168 // 124,672 bytes

__device__ __forceinline__ float lrelu(float x) {
    return fmaxf(x, 0.0f) + 0.01f * fminf(x, 0.0f);
}

// Transpose g0_w (64 x 514) into wt[c][j], c in [0,257), j in [0,128):
//   j <  64 : A-part = g0_w[j][c]        (applies to feats[m], the x_i half)
//   j >= 64 : B-part = g0_w[j-64][257+c] (applies to feats[l], the x_j half)
__global__ void k_transpose(const float* __restrict__ g0, float* __restrict__ wt) {
    __shared__ float tile[64][65];
    const int cbase = blockIdx.x * 64;
    const int jh = blockIdx.y;
    const int tid = threadIdx.x;
    for (int i = tid; i < 64 * 64; i += 256) {
        int r = i >> 6;
        int cc = i & 63;
        int c = cbase + cc;
        float v = 0.0f;
        if (c < ND) v = g0[r * (2 * ND) + jh * ND + c];
        tile[r][cc] = v;
    }
    __syncthreads();
    for (int i = tid; i < 64 * 64; i += 256) {
        int cc = i >> 6;
        int r = i & 63;
        int c = cbase + cc;
        if (c < ND) wt[c * 128 + jh * 64 + r] = tile[r][cc];
    }
}

__global__ __launch_bounds__(512, 2)
void k_main(const float* __restrict__ x_img,
            const float* __restrict__ wt,      // [257][128]
            const float* __restrict__ g0_b,
            const float* __restrict__ g1_w,
            const float* __restrict__ g1_b,
            const float* __restrict__ post_w,
            const float* __restrict__ post_b,
            const float* __restrict__ out_w,
            const float* __restrict__ out_b,
            float* __restrict__ out)
{
    extern __shared__ float smem[];
    float* h0c = smem + OFF_H0;
    float* xs  = smem + OFF_H0;   // alias, live only in phase 1
    float* red = smem + OFF_H0;   // alias, live only after phase 2
    float* Pb  = smem + OFF_P;
    float* b0s = smem + OFF_B0;
    float* sf  = smem + OFF_SF;
    float* zs  = smem + OFF_Z;

    const int tid  = threadIdx.x;
    const int b    = blockIdx.x;
    const int lane = tid & 63;
    const int wid  = tid >> 6;

    // ---- stage x slice: 6400 floats, coalesced float4 ----
    {
        const float4* src = (const float4*)(x_img + (size_t)b * (NC * NL));
        float4* dst = (float4*)xs;
        for (int i = tid; i < 1600; i += 512) dst[i] = src[i];
    }
    if (tid < 64) b0s[tid] = g0_b[tid];
    __syncthreads();

    // ---- phase 1: P[chalf][uv][p][k] partial projections ----
    // 512 threads = chalf(2) x pgrp(8: p-groups 3,3,3,3,3,3,3,4) x uv(2) x k4(16)
    {
        const int r     = tid & 255;
        const int chalf = tid >> 8;
        const int k4    = r & 15;
        const int uv    = (r >> 4) & 1;
        const int pgrp  = r >> 5;
        const int pstart = pgrp * 3;
        const bool p4   = (pgrp == 7);
        float4 a0 = {0.f,0.f,0.f,0.f}, a1 = a0, a2 = a0, a3 = a0;
        const float4* wp = ((const float4*)wt) + (uv * 16 + k4);  // row stride 32 float4
        const float* xrow = xs + pstart;
        const int c0   = chalf ? 128 : 0;
        const int cend = chalf ? 256 : 128;
        #pragma unroll 2
        for (int c = c0; c < cend; ++c) {
            const float4 w4 = wp[c * 32];
            const float f0 = xrow[c * 25 + 0];
            const float f1 = xrow[c * 25 + 1];
            const float f2 = xrow[c * 25 + 2];
            a0.x = fmaf(w4.x, f0, a0.x); a0.y = fmaf(w4.y, f0, a0.y);
            a0.z = fmaf(w4.z, f0, a0.z); a0.w = fmaf(w4.w, f0, a0.w);
            a1.x = fmaf(w4.x, f1, a1.x); a1.y = fmaf(w4.y, f1, a1.y);
            a1.z = fmaf(w4.z, f1, a1.z); a1.w = fmaf(w4.w, f1, a1.w);
            a2.x = fmaf(w4.x, f2, a2.x); a2.y = fmaf(w4.y, f2, a2.y);
            a2.z = fmaf(w4.z, f2, a2.z); a2.w = fmaf(w4.w, f2, a2.w);
            if (p4) {
                const float f3 = xrow[c * 25 + 3];
                a3.x = fmaf(w4.x, f3, a3.x); a3.y = fmaf(w4.y, f3, a3.y);
                a3.z = fmaf(w4.z, f3, a3.z); a3.w = fmaf(w4.w, f3, a3.w);
            }
        }
        if (chalf) {  // c = 256: coordinate feature f[p][256] = (float)p
            const float4 w4 = wp[256 * 32];
            const float f0 = (float)(pstart + 0);
            const float f1 = (float)(pstart + 1);
            const float f2 = (float)(pstart + 2);
            a0.x = fmaf(w4.x, f0, a0.x); a0.y = fmaf(w4.y, f0, a0.y);
            a0.z = fmaf(w4.z, f0, a0.z); a0.w = fmaf(w4.w, f0, a0.w);
            a1.x = fmaf(w4.x, f1, a1.x); a1.y = fmaf(w4.y, f1, a1.y);
            a1.z = fmaf(w4.z, f1, a1.z); a1.w = fmaf(w4.w, f1, a1.w);
            a2.x = fmaf(w4.x, f2, a2.x); a2.y = fmaf(w4.y, f2, a2.y);
            a2.z = fmaf(w4.z, f2, a2.z); a2.w = fmaf(w4.w, f2, a2.w);
            if (p4) {
                const float f3 = (float)(pstart + 3);
                a3.x = fmaf(w4.x, f3, a3.x); a3.y = fmaf(w4.y, f3, a3.y);
                a3.z = fmaf(w4.z, f3, a3.z); a3.w = fmaf(w4.w, f3, a3.w);
            }
        }
        float* dst = Pb + (chalf * 2 + uv) * 1600;
        *(float4*)&dst[(pstart + 0) * 64 + k4 * 4] = a0;
        *(float4*)&dst[(pstart + 1) * 64 + k4 * 4] = a1;
        *(float4*)&dst[(pstart + 2) * 64 + k4 * 4] = a2;
        if (p4) *(float4*)&dst[(pstart + 3) * 64 + k4 * 4] = a3;
    }
    __syncthreads();  // P ready; xs dead

    // ---- phase 2: S[j] = sum_pairs lrelu(g1[j] . h0(pair) + b1[j]) ----
    // 20 tasks = batch(10, 64 pairs each) x jhalf(2). Wave w owns T = w, w+8, w+16.
    // All of a wave's tasks share jhalf = w&1 -> acc[32] persists across tasks.
    float acc[32];
    #pragma unroll
    for (int j = 0; j < 32; ++j) acc[j] = 0.f;
    const int jbase = __builtin_amdgcn_readfirstlane((wid & 1) * 32);

    #pragma unroll 1
    for (int ch = 0; ch < 2; ++ch) {
        const int cbase = ch ? 384 : 0;   // first pair of chunk
        const int slots = ch ? 256 : 384; // pair slots in chunk
        __syncthreads();                  // prev chunk consumed
        // -- 2a: fill h0c (k4-swizzled rows) --
        const float4* P4 = (const float4*)Pb;
        const int rounds = (slots * 16) >> 9;  // 12 or 8
        #pragma unroll 1
        for (int rr = 0; rr < rounds; ++rr) {
            const int idx = rr * 512 + tid;
            const int k4 = idx & 15;
            const int lp = idx >> 4;
            int pp = cbase + lp; pp = (pp > 624) ? 624 : pp;
            const int l = (pp * 5243) >> 17;   // pp / 25
            const int m = pp - l * 25;
            const float4 u0 = P4[         m * 16 + k4];
            const float4 v0 = P4[ 400 +   l * 16 + k4];
            const float4 u1 = P4[ 800 +   m * 16 + k4];
            const float4 v1 = P4[1200 +   l * 16 + k4];
            const float4 b4 = *(const float4*)&b0s[k4 * 4];
            float4 h;
            h.x = lrelu(u0.x + u1.x + v0.x + v1.x + b4.x);
            h.y = lrelu(u0.y + u1.y + v0.y + v1.y + b4.y);
            h.z = lrelu(u0.z + u1.z + v0.z + v1.z + b4.z);
            h.w = lrelu(u0.w + u1.w + v0.w + v1.w + b4.w);
            *(float4*)&h0c[lp * 64 + ((k4 ^ (lp & 15)) << 2)] = h;
        }
        __syncthreads();
        // -- 2b: per-wave tasks, loop-swapped so LDS reads are per-k-chunk --
        // dq[16] are float4 dot accumulators (static indices -> forced VGPRs).
        // ds_reads/task: 2 jh x 4 kc x 4 = 32 (was 512 when compiler demoted h).
        #pragma unroll 1
        for (int T = wid; T < 20; T += 8) {
            const int batch = T >> 1;
            if (ch ? (batch < 6) : (batch >= 6)) continue;
            const int pp = batch * 64 + lane;
            const bool ok = pp < 625;
            const int lp = ((pp > 624) ? 624 : pp) - cbase;
            const int hb = lp * 64;
            const int sw = lp & 15;
            #pragma unroll
            for (int jh = 0; jh < 2; ++jh) {
                float4 dq[16];
                #pragma unroll
                for (int q = 0; q < 16; ++q) dq[q] = make_float4(0.f,0.f,0.f,0.f);
                #pragma unroll
                for (int kc = 0; kc < 4; ++kc) {
                    const float4 h0v = *(const float4*)&h0c[hb + (((kc*4+0) ^ sw) << 2)];
                    const float4 h1v = *(const float4*)&h0c[hb + (((kc*4+1) ^ sw) << 2)];
                    const float4 h2v = *(const float4*)&h0c[hb + (((kc*4+2) ^ sw) << 2)];
                    const float4 h3v = *(const float4*)&h0c[hb + (((kc*4+3) ^ sw) << 2)];
                    #pragma unroll
                    for (int q = 0; q < 16; ++q) {
                        const float4* __restrict__ gr =
                            (const float4*)(g1_w + (size_t)(jbase + jh * 16 + q) * 64) + kc * 4;
                        const float4 g0v = gr[0];
                        dq[q].x = fmaf(g0v.x, h0v.x, dq[q].x);
                        dq[q].y = fmaf(g0v.y, h0v.y, dq[q].y);
                        dq[q].z = fmaf(g0v.z, h0v.z, dq[q].z);
                        dq[q].w = fmaf(g0v.w, h0v.w, dq[q].w);
                        const float4 g1v = gr[1];
                        dq[q].x = fmaf(g1v.x, h1v.x, dq[q].x);
                        dq[q].y = fmaf(g1v.y, h1v.y, dq[q].y);
                        dq[q].z = fmaf(g1v.z, h1v.z, dq[q].z);
                        dq[q].w = fmaf(g1v.w, h1v.w, dq[q].w);
                        const float4 g2v = gr[2];
                        dq[q].x = fmaf(g2v.x, h2v.x, dq[q].x);
                        dq[q].y = fmaf(g2v.y, h2v.y, dq[q].y);
                        dq[q].z = fmaf(g2v.z, h2v.z, dq[q].z);
                        dq[q].w = fmaf(g2v.w, h2v.w, dq[q].w);
                        const float4 g3v = gr[3];
                        dq[q].x = fmaf(g3v.x, h3v.x, dq[q].x);
                        dq[q].y = fmaf(g3v.y, h3v.y, dq[q].y);
                        dq[q].z = fmaf(g3v.z, h3v.z, dq[q].z);
                        dq[q].w = fmaf(g3v.w, h3v.w, dq[q].w);
                    }
                }
                #pragma unroll
                for (int q = 0; q < 16; ++q) {
                    const float d = (dq[q].x + dq[q].y) + (dq[q].z + dq[q].w);
                    const float t = lrelu(d + g1_b[jbase + jh * 16 + q]);
                    acc[jh * 16 + q] += ok ? t : 0.0f;
                }
            }
        }
    }

    // ---- reduce acc across lanes & waves ----
    __syncthreads();  // h0c dead -> red usable
    {
        const int col = ((wid >> 1) << 6) + lane;  // 0..255 per jhalf group
        #pragma unroll
        for (int j = 0; j < 32; ++j)
            red[(jbase + j) * 264 + col] = acc[j];
    }
    __syncthreads();
    {
        const int j = tid >> 3, seg = tid & 7;
        const float* rp = red + j * 264 + seg;
        float s = 0.f;
        #pragma unroll
        for (int i = 0; i < 32; ++i) s += rp[i * 8];
        s += __shfl_xor(s, 1, 64);
        s += __shfl_xor(s, 2, 64);
        s += __shfl_xor(s, 4, 64);
        if (seg == 0) sf[j] = s;
    }
    __syncthreads();

    // ---- final MLP (wave 0) ----
    if (tid < 64) {
        float a = post_b[tid];
        #pragma unroll 8
        for (int k = 0; k < 64; ++k) a = fmaf(post_w[tid * 64 + k], sf[k], a);
        zs[tid] = lrelu(a);
        if (tid < 32) {
            float a2 = out_b[tid];
            #pragma unroll 8
            for (int k = 0; k < 64; ++k) a2 = fmaf(out_w[tid * 64 + k], zs[k], a2);
            out[b * NOUT + tid] = lrelu(a2);
        }
    }
}

extern "C" void kernel_launch(void* const* d_in, const int* in_sizes, int n_in,
                              void* d_out, int out_size, void* d_ws, size_t ws_size,
                              hipStream_t stream) {
    const float* x_img  = (const float*)d_in[0];
    const float* g0_w   = (const float*)d_in[1];
    const float* g0_b   = (const float*)d_in[2];
    const float* g1_w   = (const float*)d_in[3];
    const float* g1_b   = (const float*)d_in[4];
    const float* post_w = (const float*)d_in[5];
    const float* post_b = (const float*)d_in[6];
    const float* out_w  = (const float*)d_in[7];
    const float* out_b  = (const float*)d_in[8];
    float* out = (float*)d_out;
    float* wt  = (float*)d_ws;  // 257*128 fp32

    // dynamic LDS 124.7 KB > 64 KB: opt in every call (idempotent, capture-safe)
    hipFuncSetAttribute((const void*)k_main,
                        hipFuncAttributeMaxDynamicSharedMemorySize,
                        SMEM_FLOATS * 4);

    k_transpose<<<dim3(5, 2), 256, 0, stream>>>(g0_w, wt);
    k_main<<<dim3(NB), 512, SMEM_FLOATS * 4, stream>>>(x_img, wt, g0_b, g1_w, g1_b,
                                                       post_w, post_b, out_w, out_b, out);
}